// Round 1
// baseline (267.410 us; speedup 1.0000x reference)
//
#include <hip/hip_runtime.h>
#include <hip/hip_bf16.h>

// HeteroGAT: 2-relation GAT, N=100000, IN=OUT=128, E=320000/rel.
// Dtypes (R1-R4 verified): inputs f32, output f32.
// R8: 262us, aggregate top (65us): latency-bound gather chain (HBM 29%,
// VALU 51%, MFMA 0). R9: hoist score math out of aggregate -- fill computes
// e=exp(leaky(.)) edge-parallel, atomically builds per-dst denominators, and
// scatters {src,e} 8B pairs into CSR. aggregate becomes a pure pre-weighted
// gather-sum: both rels merged into one edge list, 8 edges/round branchless
// (invalid slots clamp to sorted[0] -> L1-hit dummy row, weight 0), single
// final cross-subgroup combine. 7 dispatches.

typedef __bf16 bf16x8 __attribute__((ext_vector_type(8)));
typedef float f32x4 __attribute__((ext_vector_type(4)));

#define DIM 128

// ---- prep: W^T (both rels) -> bf16 in exact B-fragment order ----
// entry e = ((rel*8 + ct)*4 + ko4)*64 + lane holds 8 bf16:
//   B[k = ko4*32 + (lane>>4)*8 + j][n = ct*16 + (lane&15)], j=0..7
__global__ __launch_bounds__(256) void prep_w_kernel(
    const float* __restrict__ W0, const float* __restrict__ W1,
    __bf16* __restrict__ wtf)
{
    const int e = blockIdx.x * 256 + threadIdx.x;   // 4096 entries
    if (e >= 4096) return;
    const int lane = e & 63;
    const int ko4  = (e >> 6) & 3;
    const int ct   = (e >> 8) & 7;
    const int rel  = e >> 11;
    const float* W = rel ? W1 : W0;
    const int n  = ct * 16 + (lane & 15);
    const int k0 = ko4 * 32 + (lane >> 4) * 8;
    bf16x8 v;
#pragma unroll
    for (int j = 0; j < 8; ++j) v[j] = (__bf16)W[(k0 + j) * DIM + n];
    *(bf16x8*)(wtf + (size_t)e * 8) = v;
}

// ---- wh_r = bf16(x) @ W_r + b_r (both rels), fused scores + edge count ----
// Block 256 = 4 waves; wave owns 16 rows; block 64 rows. No LDS for W:
// bfrags are wave-uniform coalesced 1KB global loads from wtf (L1-hit).
// A-slice (128 k) lives in 16 VGPRs bf16 across both relations.
__global__ __launch_bounds__(256) void gemm_wh_kernel(
    const float* __restrict__ x, const __bf16* __restrict__ wtf,
    const float* __restrict__ b0, const float* __restrict__ b1,
    const float* __restrict__ a0, const float* __restrict__ a1,
    const int* __restrict__ dst0, const int* __restrict__ dst1,
    unsigned* __restrict__ deg,
    __bf16* __restrict__ wh, float* __restrict__ s_src,
    float* __restrict__ s_dst, int N, int E)
{
    __shared__ __align__(16) __bf16 Cst[64 * 136];  // 17408 B C-staging
    const int tid = threadIdx.x;

    // fused per-edge degree count (independent, fire-and-forget atomics)
    {
        const int gid = blockIdx.x * 256 + tid;
        if (gid < E) {
            atomicAdd(deg + dst0[gid], 1u);
            atomicAdd(deg + N + dst1[gid], 1u);
        }
    }

    const int lane = tid & 63;
    const int wave = tid >> 6;
    const int quad = lane >> 4;
    const int mr   = lane & 15;

    const long row0 = (long)blockIdx.x * 64 + wave * 16;
    long arow = row0 + mr;
    if (arow >= N) arow = N - 1;               // clamp; results discarded
    const f32x4* xr = (const f32x4*)(x + arow * DIM);

    // full A slice for this lane: k = ko4*32 + quad*8 .. +7
    bf16x8 afrag[4];
#pragma unroll
    for (int ko4 = 0; ko4 < 4; ++ko4) {
        f32x4 lo = xr[ko4 * 8 + quad * 2], hi = xr[ko4 * 8 + quad * 2 + 1];
        afrag[ko4] = (bf16x8){ (__bf16)lo.x, (__bf16)lo.y, (__bf16)lo.z, (__bf16)lo.w,
                               (__bf16)hi.x, (__bf16)hi.y, (__bf16)hi.z, (__bf16)hi.w };
    }

    const bf16x8* wt = (const bf16x8*)wtf;

#pragma unroll
    for (int rel = 0; rel < 2; ++rel) {
        f32x4 zero = {0.f, 0.f, 0.f, 0.f};
        f32x4 acc[8];
#pragma unroll
        for (int t = 0; t < 8; ++t) acc[t] = zero;

#pragma unroll
        for (int ko4 = 0; ko4 < 4; ++ko4) {
#pragma unroll
            for (int ct = 0; ct < 8; ++ct) {
                bf16x8 bfrag = wt[((rel * 8 + ct) * 4 + ko4) * 64 + lane];
                acc[ct] = __builtin_amdgcn_mfma_f32_16x16x32_bf16(afrag[ko4], bfrag, acc[ct], 0, 0, 0);
            }
        }

        const float* bias = rel ? b1 : b0;
        const float* a    = rel ? a1 : a0;
        // C/D layout: col = ct*16+mr, row = quad*4+rr [m89-verified]
        float psr[4] = {0.f, 0.f, 0.f, 0.f};
        float pdr[4] = {0.f, 0.f, 0.f, 0.f};
#pragma unroll
        for (int ct = 0; ct < 8; ++ct) {
            const int c = ct * 16 + mr;
            const float bn = bias[c];
            const float asc = a[c], adc = a[DIM + c];
#pragma unroll
            for (int rr = 0; rr < 4; ++rr) {
                const float wv = acc[ct][rr] + bn;
                Cst[(wave * 16 + quad * 4 + rr) * 136 + c] = (__bf16)wv;
                psr[rr] += asc * wv;
                pdr[rr] += adc * wv;
            }
        }
#pragma unroll
        for (int off = 1; off < 16; off <<= 1) {
#pragma unroll
            for (int rr = 0; rr < 4; ++rr) {
                psr[rr] += __shfl_xor(psr[rr], off);
                pdr[rr] += __shfl_xor(pdr[rr], off);
            }
        }
        if (mr == 0) {
#pragma unroll
            for (int rr = 0; rr < 4; ++rr) {
                const long orow = row0 + quad * 4 + rr;
                if (orow < N) {
                    s_src[(size_t)rel * N + orow] = psr[rr];
                    s_dst[(size_t)rel * N + orow] = pdr[rr];
                }
            }
        }
        __syncthreads();                        // staging complete
        // coalesced read-back: 1024 chunks of 16B
#pragma unroll
        for (int i = 0; i < 4; ++i) {
            const int chunk = tid + 256 * i;
            const int row = chunk >> 4, c8 = chunk & 15;
            bf16x8 v = *(const bf16x8*)&Cst[row * 136 + c8 * 8];
            const long grow = (long)blockIdx.x * 64 + row;
            if (grow < N)
                *(bf16x8*)(wh + ((size_t)rel * N + grow) * DIM + c8 * 8) = v;
        }
        __syncthreads();                        // before rel1 re-stages Cst
    }
}

// ---------------- CSR scan pass 1: per-block inclusive scan ----------------
__global__ __launch_bounds__(256) void scanA_kernel(
    const unsigned* __restrict__ deg, unsigned* __restrict__ tmp,
    unsigned* __restrict__ bsum, int n)
{
    __shared__ unsigned s[256];
    const int t = threadIdx.x;
    const int i = blockIdx.x * 256 + t;
    unsigned v = (i < n) ? deg[i] : 0u;
    s[t] = v;
    __syncthreads();
#pragma unroll
    for (int off = 1; off < 256; off <<= 1) {
        unsigned add = (t >= off) ? s[t - off] : 0u;
        __syncthreads();
        s[t] += add;
        __syncthreads();
    }
    if (i < n) tmp[i] = s[t] - v;            // exclusive within block
    if (t == 255) bsum[blockIdx.x] = s[t];   // block total
}

// ---- CSR scan pass 2: each block re-scans bsum locally, writes rowptr ----
// nb <= 1024 (782 here)
__global__ __launch_bounds__(256) void scan2_kernel(
    const unsigned* __restrict__ tmp, const unsigned* __restrict__ bsum,
    const unsigned* __restrict__ deg, unsigned* __restrict__ rowptr,
    unsigned* __restrict__ cursor, int n, int nb)
{
    __shared__ unsigned s[256];
    __shared__ unsigned ex[1024];
    const int t = threadIdx.x;
    unsigned loc[4], sum = 0u;
#pragma unroll
    for (int k = 0; k < 4; ++k) {
        int idx = t * 4 + k;
        loc[k] = (idx < nb) ? bsum[idx] : 0u;
        sum += loc[k];
    }
    s[t] = sum;
    __syncthreads();
#pragma unroll
    for (int off = 1; off < 256; off <<= 1) {
        unsigned add = (t >= off) ? s[t - off] : 0u;
        __syncthreads();
        s[t] += add;
        __syncthreads();
    }
    unsigned run = s[t] - sum;
#pragma unroll
    for (int k = 0; k < 4; ++k) {
        ex[t * 4 + k] = run;
        run += loc[k];
    }
    __syncthreads();
    const unsigned pref = ex[blockIdx.x];
    const int i = blockIdx.x * 256 + t;
    if (i < n) {
        unsigned val = tmp[i] + pref;
        rowptr[i] = val;
        cursor[i] = val;
        if (i == n - 1) rowptr[n] = val + deg[i];
    }
}

// ---- CSR build + edge scores: scatter {src, e} pairs, build denominators ----
// Edge-parallel (massive TLP hides the s_src/s_dst gathers + expf that used
// to sit on aggregate's latency-critical chain). Denominator via float
// atomics: summation order differs from reference but |e| bounded (~e^5),
// well inside tolerance.
__global__ __launch_bounds__(256) void fill_kernel(
    const int* __restrict__ src0, const int* __restrict__ dst0,
    const int* __restrict__ src1, const int* __restrict__ dst1,
    const float* __restrict__ s_src, const float* __restrict__ s_dst,
    unsigned* __restrict__ cursor, float* __restrict__ denom,
    uint2* __restrict__ sorted, int N, int E)
{
    const int i = blockIdx.x * 256 + threadIdx.x;
    if (i >= E) return;
    const int s0 = src0[i], d0 = dst0[i];
    const int s1 = src1[i], d1 = dst1[i];

    float v0 = s_src[s0] + s_dst[d0];
    v0 = v0 > 0.f ? v0 : 0.01f * v0;            // leaky_relu slope 0.01
    const float e0 = __expf(v0);
    float v1 = s_src[N + s1] + s_dst[N + d1];
    v1 = v1 > 0.f ? v1 : 0.01f * v1;
    const float e1 = __expf(v1);

    atomicAdd(denom + d0, e0);
    const unsigned p0 = atomicAdd(cursor + d0, 1u);
    sorted[p0] = make_uint2((unsigned)s0, __float_as_uint(e0));

    atomicAdd(denom + N + d1, e1);
    const unsigned p1 = atomicAdd(cursor + N + d1, 1u);
    sorted[p1] = make_uint2((unsigned)s1, __float_as_uint(e1));
}

// ---------------- pre-weighted gather-sum, 8 edges/round ----------------
// One wave per dst. Both rels merged into one virtual edge list (len T);
// 4 subgroups x 2 slots = 8 edges in flight per round (avg T=6.4 -> ~1.15
// rounds). Branchless: invalid slots clamp idx to 0 (sorted[0]'s row stays
// L1-resident everywhere) with weight 0. Chain is sorted[] -> wh row -> FMA;
// scores/denoms precomputed by fill. Single cross-subgroup combine at end.
__global__ __launch_bounds__(256) void aggregate_kernel(
    const unsigned* __restrict__ rowptr, const uint2* __restrict__ sorted,
    const float* __restrict__ denom, const __bf16* __restrict__ wh,
    float* __restrict__ out, int N)
{
    const int tid  = threadIdx.x;
    const int lane = tid & 63;
    const int sub  = lane >> 4;
    const int mr   = lane & 15;
    int d = blockIdx.x * 4 + (tid >> 6);
    if (d >= N) return;
    d = __builtin_amdgcn_readfirstlane(d);      // wave-uniform -> s_loads

    const unsigned beg0 = rowptr[d],     end0 = rowptr[d + 1];
    const unsigned beg1 = rowptr[N + d], end1 = rowptr[N + d + 1];
    const unsigned len0 = end0 - beg0;
    const unsigned T    = len0 + (end1 - beg1);
    const float inv0 = (end0 > beg0) ? 1.f / denom[d]     : 0.f;
    const float inv1 = (end1 > beg1) ? 1.f / denom[N + d] : 0.f;

    float o[8];
#pragma unroll
    for (int k = 0; k < 8; ++k) o[k] = 0.f;

    const size_t whstride = (size_t)N * DIM;

    for (unsigned t0 = 0; t0 < T; t0 += 8) {
        const unsigned tA = t0 + sub, tB = tA + 4;
        const bool vA = tA < T, vB = tB < T;
        const bool rA = tA >= len0, rB = tB >= len0;

        unsigned iA = rA ? beg1 + (tA - len0) : beg0 + tA;
        unsigned iB = rB ? beg1 + (tB - len0) : beg0 + tB;
        iA = vA ? iA : 0u;
        iB = vB ? iB : 0u;

        const uint2 eA = sorted[iA];
        const uint2 eB = sorted[iB];

        const float wgtA = vA ? __uint_as_float(eA.y) * (rA ? inv1 : inv0) : 0.f;
        const float wgtB = vB ? __uint_as_float(eB.y) * (rB ? inv1 : inv0) : 0.f;

        const bf16x8 wA = *(const bf16x8*)(wh + (rA ? whstride : 0)
                                              + (size_t)eA.x * DIM + mr * 8);
        const bf16x8 wB = *(const bf16x8*)(wh + (rB ? whstride : 0)
                                              + (size_t)eB.x * DIM + mr * 8);
#pragma unroll
        for (int k = 0; k < 8; ++k) o[k] += wgtA * (float)wA[k];
#pragma unroll
        for (int k = 0; k < 8; ++k) o[k] += wgtB * (float)wB[k];
    }

    // single combine across 4 subgroups
#pragma unroll
    for (int k = 0; k < 8; ++k) {
        o[k] += __shfl_xor(o[k], 16);
        o[k] += __shfl_xor(o[k], 32);
    }

    if (sub == 0) {                             // 16 lanes cover the 512B row
        float4 v0 = {o[0], o[1], o[2], o[3]};
        float4 v1 = {o[4], o[5], o[6], o[7]};
        float* op = out + (size_t)d * DIM + mr * 8;
        *(float4*)op       = v0;
        *(float4*)(op + 4) = v1;
    }
}

extern "C" void kernel_launch(void* const* d_in, const int* in_sizes, int n_in,
                              void* d_out, int out_size, void* d_ws, size_t ws_size,
                              hipStream_t stream) {
    const float* x = (const float*)d_in[0];
    const int* srcs[2] = {(const int*)d_in[1], (const int*)d_in[3]};
    const int* dsts[2] = {(const int*)d_in[2], (const int*)d_in[4]};
    const float* Ws[2] = {(const float*)d_in[5], (const float*)d_in[8]};
    const float* Bs[2] = {(const float*)d_in[6], (const float*)d_in[9]};
    const float* As[2] = {(const float*)d_in[7], (const float*)d_in[10]};

    const int N = in_sizes[0] / DIM;
    const int E = in_sizes[1];
    const int n2 = 2 * N;
    const int nb = (n2 + 255) / 256;            // scan blocks (782)
    float* out = (float*)d_out;

    // workspace carve-up (~62 MB); all chunks 8B-aligned
    char* p = (char*)d_ws;
    __bf16*   wh     = (__bf16*)p;   p += (size_t)n2 * DIM * 2;  // wh0|wh1
    __bf16*   wtf    = (__bf16*)p;   p += (size_t)4096 * 8 * 2;  // 64KB frag-W
    float*    s_src  = (float*)p;    p += (size_t)n2 * 4;
    float*    s_dst  = (float*)p;    p += (size_t)n2 * 4;
    unsigned* deg    = (unsigned*)p; p += (size_t)n2 * 4;
    float*    denom  = (float*)p;    p += (size_t)n2 * 4;        // after deg!
    unsigned* tmp    = (unsigned*)p; p += (size_t)n2 * 4;
    unsigned* rowptr = (unsigned*)p; p += (size_t)(n2 + 2) * 4;  // pad to 8B
    unsigned* cursor = (unsigned*)p; p += (size_t)n2 * 4;
    uint2*    sorted = (uint2*)p;    p += (size_t)2 * E * 8;     // {src, e}
    unsigned* bsum   = (unsigned*)p; p += (size_t)nb * 4;

    hipMemsetAsync(deg, 0, (size_t)n2 * 4 * 2, stream);          // deg + denom
    prep_w_kernel<<<16, 256, 0, stream>>>(Ws[0], Ws[1], wtf);

    // gemm grid covers both row tiles (1563) and edge count (1250)
    gemm_wh_kernel<<<(N + 63) / 64, 256, 0, stream>>>(
        x, wtf, Bs[0], Bs[1], As[0], As[1],
        dsts[0], dsts[1], deg, wh, s_src, s_dst, N, E);

    scanA_kernel<<<nb, 256, 0, stream>>>(deg, tmp, bsum, n2);
    scan2_kernel<<<nb, 256, 0, stream>>>(tmp, bsum, deg, rowptr, cursor, n2, nb);
    fill_kernel<<<(E + 255) / 256, 256, 0, stream>>>(
        srcs[0], dsts[0], srcs[1], dsts[1], s_src, s_dst,
        cursor, denom, sorted, N, E);
    aggregate_kernel<<<(N + 3) / 4, 256, 0, stream>>>(
        rowptr, sorted, denom, wh, out, N);
}

// Round 2
// 245.796 us; speedup vs baseline: 1.0879x; 1.0879x over previous
//
#include <hip/hip_runtime.h>
#include <hip/hip_bf16.h>

// HeteroGAT: 2-relation GAT, N=100000, IN=OUT=128, E=320000/rel.
// Dtypes (R1-R4 verified): inputs f32, output f32.
// R9: 267us, fill top (65.7us): VALU 0.5%, HBM 14% -> atomic-bound (1.28M
// device atomics ~= 8/cy, cursor atomics BLOCK on return). R10: capture the
// deg atomic's return in gemm as the edge's CSR rank (coalesced store, hidden
// under MFMA); fill computes slot = rowptr[dst]+rank -- zero returning
// atomics, only fire-and-forget denom adds remain (count halved). cursor
// buffer deleted. 7 dispatches.

typedef __bf16 bf16x8 __attribute__((ext_vector_type(8)));
typedef float f32x4 __attribute__((ext_vector_type(4)));

#define DIM 128

// ---- prep: W^T (both rels) -> bf16 in exact B-fragment order ----
// entry e = ((rel*8 + ct)*4 + ko4)*64 + lane holds 8 bf16:
//   B[k = ko4*32 + (lane>>4)*8 + j][n = ct*16 + (lane&15)], j=0..7
__global__ __launch_bounds__(256) void prep_w_kernel(
    const float* __restrict__ W0, const float* __restrict__ W1,
    __bf16* __restrict__ wtf)
{
    const int e = blockIdx.x * 256 + threadIdx.x;   // 4096 entries
    if (e >= 4096) return;
    const int lane = e & 63;
    const int ko4  = (e >> 6) & 3;
    const int ct   = (e >> 8) & 7;
    const int rel  = e >> 11;
    const float* W = rel ? W1 : W0;
    const int n  = ct * 16 + (lane & 15);
    const int k0 = ko4 * 32 + (lane >> 4) * 8;
    bf16x8 v;
#pragma unroll
    for (int j = 0; j < 8; ++j) v[j] = (__bf16)W[(k0 + j) * DIM + n];
    *(bf16x8*)(wtf + (size_t)e * 8) = v;
}

// ---- wh_r = bf16(x) @ W_r + b_r (both rels), fused scores + deg/rank ----
// Block 256 = 4 waves; wave owns 16 rows; block 64 rows. No LDS for W:
// bfrags are wave-uniform coalesced 1KB global loads from wtf (L1-hit).
// Degree atomics now RETURN the per-edge rank (CSR slot offset); the ~700cy
// round-trip overlaps the MFMA work of co-resident waves.
__global__ __launch_bounds__(256) void gemm_wh_kernel(
    const float* __restrict__ x, const __bf16* __restrict__ wtf,
    const float* __restrict__ b0, const float* __restrict__ b1,
    const float* __restrict__ a0, const float* __restrict__ a1,
    const int* __restrict__ dst0, const int* __restrict__ dst1,
    unsigned* __restrict__ deg, unsigned* __restrict__ rank,
    __bf16* __restrict__ wh, float* __restrict__ s_src,
    float* __restrict__ s_dst, int N, int E)
{
    __shared__ __align__(16) __bf16 Cst[64 * 136];  // 17408 B C-staging
    const int tid = threadIdx.x;

    // fused per-edge degree count + rank capture
    {
        const int gid = blockIdx.x * 256 + tid;
        if (gid < E) {
            rank[gid]     = atomicAdd(deg + dst0[gid], 1u);
            rank[E + gid] = atomicAdd(deg + N + dst1[gid], 1u);
        }
    }

    const int lane = tid & 63;
    const int wave = tid >> 6;
    const int quad = lane >> 4;
    const int mr   = lane & 15;

    const long row0 = (long)blockIdx.x * 64 + wave * 16;
    long arow = row0 + mr;
    if (arow >= N) arow = N - 1;               // clamp; results discarded
    const f32x4* xr = (const f32x4*)(x + arow * DIM);

    // full A slice for this lane: k = ko4*32 + quad*8 .. +7
    bf16x8 afrag[4];
#pragma unroll
    for (int ko4 = 0; ko4 < 4; ++ko4) {
        f32x4 lo = xr[ko4 * 8 + quad * 2], hi = xr[ko4 * 8 + quad * 2 + 1];
        afrag[ko4] = (bf16x8){ (__bf16)lo.x, (__bf16)lo.y, (__bf16)lo.z, (__bf16)lo.w,
                               (__bf16)hi.x, (__bf16)hi.y, (__bf16)hi.z, (__bf16)hi.w };
    }

    const bf16x8* wt = (const bf16x8*)wtf;

#pragma unroll
    for (int rel = 0; rel < 2; ++rel) {
        f32x4 zero = {0.f, 0.f, 0.f, 0.f};
        f32x4 acc[8];
#pragma unroll
        for (int t = 0; t < 8; ++t) acc[t] = zero;

#pragma unroll
        for (int ko4 = 0; ko4 < 4; ++ko4) {
#pragma unroll
            for (int ct = 0; ct < 8; ++ct) {
                bf16x8 bfrag = wt[((rel * 8 + ct) * 4 + ko4) * 64 + lane];
                acc[ct] = __builtin_amdgcn_mfma_f32_16x16x32_bf16(afrag[ko4], bfrag, acc[ct], 0, 0, 0);
            }
        }

        const float* bias = rel ? b1 : b0;
        const float* a    = rel ? a1 : a0;
        // C/D layout: col = ct*16+mr, row = quad*4+rr [m89-verified]
        float psr[4] = {0.f, 0.f, 0.f, 0.f};
        float pdr[4] = {0.f, 0.f, 0.f, 0.f};
#pragma unroll
        for (int ct = 0; ct < 8; ++ct) {
            const int c = ct * 16 + mr;
            const float bn = bias[c];
            const float asc = a[c], adc = a[DIM + c];
#pragma unroll
            for (int rr = 0; rr < 4; ++rr) {
                const float wv = acc[ct][rr] + bn;
                Cst[(wave * 16 + quad * 4 + rr) * 136 + c] = (__bf16)wv;
                psr[rr] += asc * wv;
                pdr[rr] += adc * wv;
            }
        }
#pragma unroll
        for (int off = 1; off < 16; off <<= 1) {
#pragma unroll
            for (int rr = 0; rr < 4; ++rr) {
                psr[rr] += __shfl_xor(psr[rr], off);
                pdr[rr] += __shfl_xor(pdr[rr], off);
            }
        }
        if (mr == 0) {
#pragma unroll
            for (int rr = 0; rr < 4; ++rr) {
                const long orow = row0 + quad * 4 + rr;
                if (orow < N) {
                    s_src[(size_t)rel * N + orow] = psr[rr];
                    s_dst[(size_t)rel * N + orow] = pdr[rr];
                }
            }
        }
        __syncthreads();                        // staging complete
        // coalesced read-back: 1024 chunks of 16B
#pragma unroll
        for (int i = 0; i < 4; ++i) {
            const int chunk = tid + 256 * i;
            const int row = chunk >> 4, c8 = chunk & 15;
            bf16x8 v = *(const bf16x8*)&Cst[row * 136 + c8 * 8];
            const long grow = (long)blockIdx.x * 64 + row;
            if (grow < N)
                *(bf16x8*)(wh + ((size_t)rel * N + grow) * DIM + c8 * 8) = v;
        }
        __syncthreads();                        // before rel1 re-stages Cst
    }
}

// ---------------- CSR scan pass 1: per-block inclusive scan ----------------
__global__ __launch_bounds__(256) void scanA_kernel(
    const unsigned* __restrict__ deg, unsigned* __restrict__ tmp,
    unsigned* __restrict__ bsum, int n)
{
    __shared__ unsigned s[256];
    const int t = threadIdx.x;
    const int i = blockIdx.x * 256 + t;
    unsigned v = (i < n) ? deg[i] : 0u;
    s[t] = v;
    __syncthreads();
#pragma unroll
    for (int off = 1; off < 256; off <<= 1) {
        unsigned add = (t >= off) ? s[t - off] : 0u;
        __syncthreads();
        s[t] += add;
        __syncthreads();
    }
    if (i < n) tmp[i] = s[t] - v;            // exclusive within block
    if (t == 255) bsum[blockIdx.x] = s[t];   // block total
}

// ---- CSR scan pass 2: each block re-scans bsum locally, writes rowptr ----
// nb <= 1024 (782 here)
__global__ __launch_bounds__(256) void scan2_kernel(
    const unsigned* __restrict__ tmp, const unsigned* __restrict__ bsum,
    const unsigned* __restrict__ deg, unsigned* __restrict__ rowptr,
    int n, int nb)
{
    __shared__ unsigned s[256];
    __shared__ unsigned ex[1024];
    const int t = threadIdx.x;
    unsigned loc[4], sum = 0u;
#pragma unroll
    for (int k = 0; k < 4; ++k) {
        int idx = t * 4 + k;
        loc[k] = (idx < nb) ? bsum[idx] : 0u;
        sum += loc[k];
    }
    s[t] = sum;
    __syncthreads();
#pragma unroll
    for (int off = 1; off < 256; off <<= 1) {
        unsigned add = (t >= off) ? s[t - off] : 0u;
        __syncthreads();
        s[t] += add;
        __syncthreads();
    }
    unsigned run = s[t] - sum;
#pragma unroll
    for (int k = 0; k < 4; ++k) {
        ex[t * 4 + k] = run;
        run += loc[k];
    }
    __syncthreads();
    const unsigned pref = ex[blockIdx.x];
    const int i = blockIdx.x * 256 + t;
    if (i < n) {
        unsigned val = tmp[i] + pref;
        rowptr[i] = val;
        if (i == n - 1) rowptr[n] = val + deg[i];
    }
}

// ---- CSR build + edge scores: deterministic slots, no returning atomics ----
// slot = rowptr[dst] + rank (rank captured in gemm's deg atomic). Chain is
// now all independent loads -> expf -> fire-and-forget store + denom atomic.
// Denominator summation order differs from reference but |e| bounded (~e^5),
// well inside tolerance.
__global__ __launch_bounds__(256) void fill_kernel(
    const int* __restrict__ src0, const int* __restrict__ dst0,
    const int* __restrict__ src1, const int* __restrict__ dst1,
    const float* __restrict__ s_src, const float* __restrict__ s_dst,
    const unsigned* __restrict__ rowptr, const unsigned* __restrict__ rank,
    float* __restrict__ denom, uint2* __restrict__ sorted, int N, int E)
{
    const int i = blockIdx.x * 256 + threadIdx.x;
    if (i >= E) return;
    const int s0 = src0[i], d0 = dst0[i];
    const int s1 = src1[i], d1 = dst1[i];
    const unsigned r0 = rank[i], r1 = rank[E + i];
    const unsigned p0 = rowptr[d0] + r0;
    const unsigned p1 = rowptr[N + d1] + r1;

    float v0 = s_src[s0] + s_dst[d0];
    v0 = v0 > 0.f ? v0 : 0.01f * v0;            // leaky_relu slope 0.01
    const float e0 = __expf(v0);
    float v1 = s_src[N + s1] + s_dst[N + d1];
    v1 = v1 > 0.f ? v1 : 0.01f * v1;
    const float e1 = __expf(v1);

    sorted[p0] = make_uint2((unsigned)s0, __float_as_uint(e0));
    sorted[p1] = make_uint2((unsigned)s1, __float_as_uint(e1));
    atomicAdd(denom + d0, e0);                  // fire-and-forget
    atomicAdd(denom + N + d1, e1);
}

// ---------------- pre-weighted gather-sum, 8 edges/round ----------------
// One wave per dst. Both rels merged into one virtual edge list (len T);
// 4 subgroups x 2 slots = 8 edges in flight per round (avg T=6.4 -> ~1.15
// rounds). Branchless: invalid slots clamp idx to 0 (sorted[0]'s row stays
// L1-resident everywhere) with weight 0. Chain is sorted[] -> wh row -> FMA;
// scores/denoms precomputed by fill. Single cross-subgroup combine at end.
__global__ __launch_bounds__(256) void aggregate_kernel(
    const unsigned* __restrict__ rowptr, const uint2* __restrict__ sorted,
    const float* __restrict__ denom, const __bf16* __restrict__ wh,
    float* __restrict__ out, int N)
{
    const int tid  = threadIdx.x;
    const int lane = tid & 63;
    const int sub  = lane >> 4;
    const int mr   = lane & 15;
    int d = blockIdx.x * 4 + (tid >> 6);
    if (d >= N) return;
    d = __builtin_amdgcn_readfirstlane(d);      // wave-uniform -> s_loads

    const unsigned beg0 = rowptr[d],     end0 = rowptr[d + 1];
    const unsigned beg1 = rowptr[N + d], end1 = rowptr[N + d + 1];
    const unsigned len0 = end0 - beg0;
    const unsigned T    = len0 + (end1 - beg1);
    const float inv0 = (end0 > beg0) ? 1.f / denom[d]     : 0.f;
    const float inv1 = (end1 > beg1) ? 1.f / denom[N + d] : 0.f;

    float o[8];
#pragma unroll
    for (int k = 0; k < 8; ++k) o[k] = 0.f;

    const size_t whstride = (size_t)N * DIM;

    for (unsigned t0 = 0; t0 < T; t0 += 8) {
        const unsigned tA = t0 + sub, tB = tA + 4;
        const bool vA = tA < T, vB = tB < T;
        const bool rA = tA >= len0, rB = tB >= len0;

        unsigned iA = rA ? beg1 + (tA - len0) : beg0 + tA;
        unsigned iB = rB ? beg1 + (tB - len0) : beg0 + tB;
        iA = vA ? iA : 0u;
        iB = vB ? iB : 0u;

        const uint2 eA = sorted[iA];
        const uint2 eB = sorted[iB];

        const float wgtA = vA ? __uint_as_float(eA.y) * (rA ? inv1 : inv0) : 0.f;
        const float wgtB = vB ? __uint_as_float(eB.y) * (rB ? inv1 : inv0) : 0.f;

        const bf16x8 wA = *(const bf16x8*)(wh + (rA ? whstride : 0)
                                              + (size_t)eA.x * DIM + mr * 8);
        const bf16x8 wB = *(const bf16x8*)(wh + (rB ? whstride : 0)
                                              + (size_t)eB.x * DIM + mr * 8);
#pragma unroll
        for (int k = 0; k < 8; ++k) o[k] += wgtA * (float)wA[k];
#pragma unroll
        for (int k = 0; k < 8; ++k) o[k] += wgtB * (float)wB[k];
    }

    // single combine across 4 subgroups
#pragma unroll
    for (int k = 0; k < 8; ++k) {
        o[k] += __shfl_xor(o[k], 16);
        o[k] += __shfl_xor(o[k], 32);
    }

    if (sub == 0) {                             // 16 lanes cover the 512B row
        float4 v0 = {o[0], o[1], o[2], o[3]};
        float4 v1 = {o[4], o[5], o[6], o[7]};
        float* op = out + (size_t)d * DIM + mr * 8;
        *(float4*)op       = v0;
        *(float4*)(op + 4) = v1;
    }
}

extern "C" void kernel_launch(void* const* d_in, const int* in_sizes, int n_in,
                              void* d_out, int out_size, void* d_ws, size_t ws_size,
                              hipStream_t stream) {
    const float* x = (const float*)d_in[0];
    const int* srcs[2] = {(const int*)d_in[1], (const int*)d_in[3]};
    const int* dsts[2] = {(const int*)d_in[2], (const int*)d_in[4]};
    const float* Ws[2] = {(const float*)d_in[5], (const float*)d_in[8]};
    const float* Bs[2] = {(const float*)d_in[6], (const float*)d_in[9]};
    const float* As[2] = {(const float*)d_in[7], (const float*)d_in[10]};

    const int N = in_sizes[0] / DIM;
    const int E = in_sizes[1];
    const int n2 = 2 * N;
    const int nb = (n2 + 255) / 256;            // scan blocks (782)
    float* out = (float*)d_out;

    // workspace carve-up (~64 MB); all chunks 8B-aligned
    char* p = (char*)d_ws;
    __bf16*   wh     = (__bf16*)p;   p += (size_t)n2 * DIM * 2;  // wh0|wh1
    __bf16*   wtf    = (__bf16*)p;   p += (size_t)4096 * 8 * 2;  // 64KB frag-W
    float*    s_src  = (float*)p;    p += (size_t)n2 * 4;
    float*    s_dst  = (float*)p;    p += (size_t)n2 * 4;
    unsigned* deg    = (unsigned*)p; p += (size_t)n2 * 4;
    float*    denom  = (float*)p;    p += (size_t)n2 * 4;        // after deg!
    unsigned* tmp    = (unsigned*)p; p += (size_t)n2 * 4;
    unsigned* rowptr = (unsigned*)p; p += (size_t)(n2 + 2) * 4;  // pad to 8B
    unsigned* rank   = (unsigned*)p; p += (size_t)2 * E * 4;     // per-edge rank
    uint2*    sorted = (uint2*)p;    p += (size_t)2 * E * 8;     // {src, e}
    unsigned* bsum   = (unsigned*)p; p += (size_t)nb * 4;

    hipMemsetAsync(deg, 0, (size_t)n2 * 4 * 2, stream);          // deg + denom
    prep_w_kernel<<<16, 256, 0, stream>>>(Ws[0], Ws[1], wtf);

    // gemm grid covers both row tiles (1563) and edge count (1250)
    gemm_wh_kernel<<<(N + 63) / 64, 256, 0, stream>>>(
        x, wtf, Bs[0], Bs[1], As[0], As[1],
        dsts[0], dsts[1], deg, rank, wh, s_src, s_dst, N, E);

    scanA_kernel<<<nb, 256, 0, stream>>>(deg, tmp, bsum, n2);
    scan2_kernel<<<nb, 256, 0, stream>>>(tmp, bsum, deg, rowptr, n2, nb);
    fill_kernel<<<(E + 255) / 256, 256, 0, stream>>>(
        srcs[0], dsts[0], srcs[1], dsts[1], s_src, s_dst,
        rowptr, rank, denom, sorted, N, E);
    aggregate_kernel<<<(N + 3) / 4, 256, 0, stream>>>(
        rowptr, sorted, denom, wh, out, N);
}

// Round 3
// 232.211 us; speedup vs baseline: 1.1516x; 1.0585x over previous
//
#include <hip/hip_runtime.h>
#include <hip/hip_bf16.h>

// HeteroGAT: 2-relation GAT, N=100000, IN=OUT=128, E=320000/rel.
// Dtypes (R1-R4 verified): inputs f32, output f32.
// R10: 245.8us, gemm top (76us): MFMA 3%, VALU 8%, HBM 17%, occ 29% -- all
// low; identical time to R8's structurally-different gemm => shared resource
// = 640K scattered device atomics (R9 calib: ~8 atomics/cy device-wide).
// R11: (1) aggregate computes softmax denominators inline (dual per-rel
// accumulators a0/a1 + l0/l1) -> fill is now 100% atomic-free; (2) deg bins
// spread x16 (64B sectors) to test/exploit line-contention hypothesis for
// gemm's remaining rank atomics; (3) denom buffer deleted. 7 dispatches.

typedef __bf16 bf16x8 __attribute__((ext_vector_type(8)));
typedef float f32x4 __attribute__((ext_vector_type(4)));

#define DIM 128
#define SPREAD 16   // deg bin spacing (x4B = 64B sector per bin)

// ---- prep: W^T (both rels) -> bf16 in exact B-fragment order ----
// entry e = ((rel*8 + ct)*4 + ko4)*64 + lane holds 8 bf16:
//   B[k = ko4*32 + (lane>>4)*8 + j][n = ct*16 + (lane&15)], j=0..7
__global__ __launch_bounds__(256) void prep_w_kernel(
    const float* __restrict__ W0, const float* __restrict__ W1,
    __bf16* __restrict__ wtf)
{
    const int e = blockIdx.x * 256 + threadIdx.x;   // 4096 entries
    if (e >= 4096) return;
    const int lane = e & 63;
    const int ko4  = (e >> 6) & 3;
    const int ct   = (e >> 8) & 7;
    const int rel  = e >> 11;
    const float* W = rel ? W1 : W0;
    const int n  = ct * 16 + (lane & 15);
    const int k0 = ko4 * 32 + (lane >> 4) * 8;
    bf16x8 v;
#pragma unroll
    for (int j = 0; j < 8; ++j) v[j] = (__bf16)W[(k0 + j) * DIM + n];
    *(bf16x8*)(wtf + (size_t)e * 8) = v;
}

// ---- wh_r = bf16(x) @ W_r + b_r (both rels), fused scores + deg/rank ----
// Block 256 = 4 waves; wave owns 16 rows; block 64 rows. No LDS for W:
// bfrags are wave-uniform coalesced 1KB global loads from wtf (L1-hit).
// Degree atomics RETURN the per-edge rank; bins spread to one 64B sector
// each so concurrent atomics don't serialize on shared cache lines.
__global__ __launch_bounds__(256) void gemm_wh_kernel(
    const float* __restrict__ x, const __bf16* __restrict__ wtf,
    const float* __restrict__ b0, const float* __restrict__ b1,
    const float* __restrict__ a0, const float* __restrict__ a1,
    const int* __restrict__ dst0, const int* __restrict__ dst1,
    unsigned* __restrict__ deg, unsigned* __restrict__ rank,
    __bf16* __restrict__ wh, float* __restrict__ s_src,
    float* __restrict__ s_dst, int N, int E)
{
    __shared__ __align__(16) __bf16 Cst[64 * 136];  // 17408 B C-staging
    const int tid = threadIdx.x;

    // fused per-edge degree count + rank capture (spread bins)
    {
        const int gid = blockIdx.x * 256 + tid;
        if (gid < E) {
            rank[gid]     = atomicAdd(deg + (size_t)dst0[gid] * SPREAD, 1u);
            rank[E + gid] = atomicAdd(deg + ((size_t)N + dst1[gid]) * SPREAD, 1u);
        }
    }

    const int lane = tid & 63;
    const int wave = tid >> 6;
    const int quad = lane >> 4;
    const int mr   = lane & 15;

    const long row0 = (long)blockIdx.x * 64 + wave * 16;
    long arow = row0 + mr;
    if (arow >= N) arow = N - 1;               // clamp; results discarded
    const f32x4* xr = (const f32x4*)(x + arow * DIM);

    // full A slice for this lane: k = ko4*32 + quad*8 .. +7
    bf16x8 afrag[4];
#pragma unroll
    for (int ko4 = 0; ko4 < 4; ++ko4) {
        f32x4 lo = xr[ko4 * 8 + quad * 2], hi = xr[ko4 * 8 + quad * 2 + 1];
        afrag[ko4] = (bf16x8){ (__bf16)lo.x, (__bf16)lo.y, (__bf16)lo.z, (__bf16)lo.w,
                               (__bf16)hi.x, (__bf16)hi.y, (__bf16)hi.z, (__bf16)hi.w };
    }

    const bf16x8* wt = (const bf16x8*)wtf;

#pragma unroll
    for (int rel = 0; rel < 2; ++rel) {
        f32x4 zero = {0.f, 0.f, 0.f, 0.f};
        f32x4 acc[8];
#pragma unroll
        for (int t = 0; t < 8; ++t) acc[t] = zero;

#pragma unroll
        for (int ko4 = 0; ko4 < 4; ++ko4) {
#pragma unroll
            for (int ct = 0; ct < 8; ++ct) {
                bf16x8 bfrag = wt[((rel * 8 + ct) * 4 + ko4) * 64 + lane];
                acc[ct] = __builtin_amdgcn_mfma_f32_16x16x32_bf16(afrag[ko4], bfrag, acc[ct], 0, 0, 0);
            }
        }

        const float* bias = rel ? b1 : b0;
        const float* a    = rel ? a1 : a0;
        // C/D layout: col = ct*16+mr, row = quad*4+rr [m89-verified]
        float psr[4] = {0.f, 0.f, 0.f, 0.f};
        float pdr[4] = {0.f, 0.f, 0.f, 0.f};
#pragma unroll
        for (int ct = 0; ct < 8; ++ct) {
            const int c = ct * 16 + mr;
            const float bn = bias[c];
            const float asc = a[c], adc = a[DIM + c];
#pragma unroll
            for (int rr = 0; rr < 4; ++rr) {
                const float wv = acc[ct][rr] + bn;
                Cst[(wave * 16 + quad * 4 + rr) * 136 + c] = (__bf16)wv;
                psr[rr] += asc * wv;
                pdr[rr] += adc * wv;
            }
        }
#pragma unroll
        for (int off = 1; off < 16; off <<= 1) {
#pragma unroll
            for (int rr = 0; rr < 4; ++rr) {
                psr[rr] += __shfl_xor(psr[rr], off);
                pdr[rr] += __shfl_xor(pdr[rr], off);
            }
        }
        if (mr == 0) {
#pragma unroll
            for (int rr = 0; rr < 4; ++rr) {
                const long orow = row0 + quad * 4 + rr;
                if (orow < N) {
                    s_src[(size_t)rel * N + orow] = psr[rr];
                    s_dst[(size_t)rel * N + orow] = pdr[rr];
                }
            }
        }
        __syncthreads();                        // staging complete
        // coalesced read-back: 1024 chunks of 16B
#pragma unroll
        for (int i = 0; i < 4; ++i) {
            const int chunk = tid + 256 * i;
            const int row = chunk >> 4, c8 = chunk & 15;
            bf16x8 v = *(const bf16x8*)&Cst[row * 136 + c8 * 8];
            const long grow = (long)blockIdx.x * 64 + row;
            if (grow < N)
                *(bf16x8*)(wh + ((size_t)rel * N + grow) * DIM + c8 * 8) = v;
        }
        __syncthreads();                        // before rel1 re-stages Cst
    }
}

// ---------------- CSR scan pass 1: per-block inclusive scan ----------------
__global__ __launch_bounds__(256) void scanA_kernel(
    const unsigned* __restrict__ deg, unsigned* __restrict__ tmp,
    unsigned* __restrict__ bsum, int n)
{
    __shared__ unsigned s[256];
    const int t = threadIdx.x;
    const int i = blockIdx.x * 256 + t;
    unsigned v = (i < n) ? deg[(size_t)i * SPREAD] : 0u;
    s[t] = v;
    __syncthreads();
#pragma unroll
    for (int off = 1; off < 256; off <<= 1) {
        unsigned add = (t >= off) ? s[t - off] : 0u;
        __syncthreads();
        s[t] += add;
        __syncthreads();
    }
    if (i < n) tmp[i] = s[t] - v;            // exclusive within block
    if (t == 255) bsum[blockIdx.x] = s[t];   // block total
}

// ---- CSR scan pass 2: each block re-scans bsum locally, writes rowptr ----
// nb <= 1024 (782 here)
__global__ __launch_bounds__(256) void scan2_kernel(
    const unsigned* __restrict__ tmp, const unsigned* __restrict__ bsum,
    const unsigned* __restrict__ deg, unsigned* __restrict__ rowptr,
    int n, int nb)
{
    __shared__ unsigned s[256];
    __shared__ unsigned ex[1024];
    const int t = threadIdx.x;
    unsigned loc[4], sum = 0u;
#pragma unroll
    for (int k = 0; k < 4; ++k) {
        int idx = t * 4 + k;
        loc[k] = (idx < nb) ? bsum[idx] : 0u;
        sum += loc[k];
    }
    s[t] = sum;
    __syncthreads();
#pragma unroll
    for (int off = 1; off < 256; off <<= 1) {
        unsigned add = (t >= off) ? s[t - off] : 0u;
        __syncthreads();
        s[t] += add;
        __syncthreads();
    }
    unsigned run = s[t] - sum;
#pragma unroll
    for (int k = 0; k < 4; ++k) {
        ex[t * 4 + k] = run;
        run += loc[k];
    }
    __syncthreads();
    const unsigned pref = ex[blockIdx.x];
    const int i = blockIdx.x * 256 + t;
    if (i < n) {
        unsigned val = tmp[i] + pref;
        rowptr[i] = val;
        if (i == n - 1) rowptr[n] = val + deg[(size_t)i * SPREAD];
    }
}

// ---- CSR build + edge scores: fully atomic-free streaming ----
// slot = rowptr[dst] + rank (rank captured in gemm's deg atomic). Chain is
// independent loads -> expf -> fire-and-forget store. Denominators now
// computed inline by aggregate.
__global__ __launch_bounds__(256) void fill_kernel(
    const int* __restrict__ src0, const int* __restrict__ dst0,
    const int* __restrict__ src1, const int* __restrict__ dst1,
    const float* __restrict__ s_src, const float* __restrict__ s_dst,
    const unsigned* __restrict__ rowptr, const unsigned* __restrict__ rank,
    uint2* __restrict__ sorted, int N, int E)
{
    const int i = blockIdx.x * 256 + threadIdx.x;
    if (i >= E) return;
    const int s0 = src0[i], d0 = dst0[i];
    const int s1 = src1[i], d1 = dst1[i];
    const unsigned p0 = rowptr[d0] + rank[i];
    const unsigned p1 = rowptr[N + d1] + rank[E + i];

    float v0 = s_src[s0] + s_dst[d0];
    v0 = v0 > 0.f ? v0 : 0.01f * v0;            // leaky_relu slope 0.01
    const float e0 = __expf(v0);
    float v1 = s_src[N + s1] + s_dst[N + d1];
    v1 = v1 > 0.f ? v1 : 0.01f * v1;
    const float e1 = __expf(v1);

    sorted[p0] = make_uint2((unsigned)s0, __float_as_uint(e0));
    sorted[p1] = make_uint2((unsigned)s1, __float_as_uint(e1));
}

// ---------------- gather-sum with inline softmax denominators ----------------
// One wave per dst. Both rels merged into one virtual edge list (len T);
// 4 subgroups x 2 slots = 8 edges in flight per round. Branchless: invalid
// slots clamp idx to 0 (L1-hit dummy row) with weight 0. Per-rel unnormalized
// accumulators a0/a1 + denominators l0/l1 built inline (rel select via zeroed
// weights); single cross-subgroup combine of 18 values, normalize, write.
__global__ __launch_bounds__(256) void aggregate_kernel(
    const unsigned* __restrict__ rowptr, const uint2* __restrict__ sorted,
    const __bf16* __restrict__ wh, float* __restrict__ out, int N)
{
    const int tid  = threadIdx.x;
    const int lane = tid & 63;
    const int sub  = lane >> 4;
    const int mr   = lane & 15;
    int d = blockIdx.x * 4 + (tid >> 6);
    if (d >= N) return;
    d = __builtin_amdgcn_readfirstlane(d);      // wave-uniform -> s_loads

    const unsigned beg0 = rowptr[d],     end0 = rowptr[d + 1];
    const unsigned beg1 = rowptr[N + d], end1 = rowptr[N + d + 1];
    const unsigned len0 = end0 - beg0;
    const unsigned T    = len0 + (end1 - beg1);

    float acc0[8], acc1[8], l0 = 0.f, l1 = 0.f;
#pragma unroll
    for (int k = 0; k < 8; ++k) { acc0[k] = 0.f; acc1[k] = 0.f; }

    const size_t whstride = (size_t)N * DIM;

    for (unsigned t0 = 0; t0 < T; t0 += 8) {
        const unsigned tA = t0 + sub, tB = tA + 4;
        const bool vA = tA < T, vB = tB < T;
        const bool rA = tA >= len0, rB = tB >= len0;

        unsigned iA = rA ? beg1 + (tA - len0) : beg0 + tA;
        unsigned iB = rB ? beg1 + (tB - len0) : beg0 + tB;
        iA = vA ? iA : 0u;
        iB = vB ? iB : 0u;

        const uint2 eA = sorted[iA];
        const uint2 eB = sorted[iB];

        const float evA = vA ? __uint_as_float(eA.y) : 0.f;
        const float evB = vB ? __uint_as_float(eB.y) : 0.f;
        const float wA0 = rA ? 0.f : evA, wA1 = rA ? evA : 0.f;
        const float wB0 = rB ? 0.f : evB, wB1 = rB ? evB : 0.f;
        l0 += wA0 + wB0;
        l1 += wA1 + wB1;

        const bf16x8 wA = *(const bf16x8*)(wh + (rA ? whstride : 0)
                                              + (size_t)eA.x * DIM + mr * 8);
        const bf16x8 wB = *(const bf16x8*)(wh + (rB ? whstride : 0)
                                              + (size_t)eB.x * DIM + mr * 8);
#pragma unroll
        for (int k = 0; k < 8; ++k) {
            const float fA = (float)wA[k], fB = (float)wB[k];
            acc0[k] += wA0 * fA + wB0 * fB;
            acc1[k] += wA1 * fA + wB1 * fB;
        }
    }

    // single combine across 4 subgroups (16+2 values)
#pragma unroll
    for (int k = 0; k < 8; ++k) {
        acc0[k] += __shfl_xor(acc0[k], 16);
        acc0[k] += __shfl_xor(acc0[k], 32);
        acc1[k] += __shfl_xor(acc1[k], 16);
        acc1[k] += __shfl_xor(acc1[k], 32);
    }
    l0 += __shfl_xor(l0, 16); l0 += __shfl_xor(l0, 32);
    l1 += __shfl_xor(l1, 16); l1 += __shfl_xor(l1, 32);

    const float inv0 = l0 > 0.f ? 1.f / l0 : 0.f;
    const float inv1 = l1 > 0.f ? 1.f / l1 : 0.f;

    if (sub == 0) {                             // 16 lanes cover the 512B row
        float o[8];
#pragma unroll
        for (int k = 0; k < 8; ++k) o[k] = acc0[k] * inv0 + acc1[k] * inv1;
        float4 v0 = {o[0], o[1], o[2], o[3]};
        float4 v1 = {o[4], o[5], o[6], o[7]};
        float* op = out + (size_t)d * DIM + mr * 8;
        *(float4*)op       = v0;
        *(float4*)(op + 4) = v1;
    }
}

extern "C" void kernel_launch(void* const* d_in, const int* in_sizes, int n_in,
                              void* d_out, int out_size, void* d_ws, size_t ws_size,
                              hipStream_t stream) {
    const float* x = (const float*)d_in[0];
    const int* srcs[2] = {(const int*)d_in[1], (const int*)d_in[3]};
    const int* dsts[2] = {(const int*)d_in[2], (const int*)d_in[4]};
    const float* Ws[2] = {(const float*)d_in[5], (const float*)d_in[8]};
    const float* Bs[2] = {(const float*)d_in[6], (const float*)d_in[9]};
    const float* As[2] = {(const float*)d_in[7], (const float*)d_in[10]};

    const int N = in_sizes[0] / DIM;
    const int E = in_sizes[1];
    const int n2 = 2 * N;
    const int nb = (n2 + 255) / 256;            // scan blocks (782)
    float* out = (float*)d_out;

    // workspace carve-up (~75 MB); all chunks 8B-aligned
    char* p = (char*)d_ws;
    __bf16*   wh     = (__bf16*)p;   p += (size_t)n2 * DIM * 2;       // wh0|wh1
    __bf16*   wtf    = (__bf16*)p;   p += (size_t)4096 * 8 * 2;       // 64KB frag-W
    float*    s_src  = (float*)p;    p += (size_t)n2 * 4;
    float*    s_dst  = (float*)p;    p += (size_t)n2 * 4;
    unsigned* deg    = (unsigned*)p; p += (size_t)n2 * SPREAD * 4;    // 12.8MB spread
    unsigned* tmp    = (unsigned*)p; p += (size_t)n2 * 4;
    unsigned* rowptr = (unsigned*)p; p += (size_t)(n2 + 2) * 4;       // pad to 8B
    unsigned* rank   = (unsigned*)p; p += (size_t)2 * E * 4;          // per-edge rank
    uint2*    sorted = (uint2*)p;    p += (size_t)2 * E * 8;          // {src, e}
    unsigned* bsum   = (unsigned*)p; p += (size_t)nb * 4;

    hipMemsetAsync(deg, 0, (size_t)n2 * SPREAD * 4, stream);
    prep_w_kernel<<<16, 256, 0, stream>>>(Ws[0], Ws[1], wtf);

    // gemm grid covers both row tiles (1563) and edge count (1250)
    gemm_wh_kernel<<<(N + 63) / 64, 256, 0, stream>>>(
        x, wtf, Bs[0], Bs[1], As[0], As[1],
        dsts[0], dsts[1], deg, rank, wh, s_src, s_dst, N, E);

    scanA_kernel<<<nb, 256, 0, stream>>>(deg, tmp, bsum, n2);
    scan2_kernel<<<nb, 256, 0, stream>>>(tmp, bsum, deg, rowptr, n2, nb);
    fill_kernel<<<(E + 255) / 256, 256, 0, stream>>>(
        srcs[0], dsts[0], srcs[1], dsts[1], s_src, s_dst,
        rowptr, rank, sorted, N, E);
    aggregate_kernel<<<(N + 3) / 4, 256, 0, stream>>>(
        rowptr, sorted, wh, out, N);
}

// Round 4
// 228.104 us; speedup vs baseline: 1.1723x; 1.0180x over previous
//
#include <hip/hip_runtime.h>
#include <hip/hip_bf16.h>

// HeteroGAT: 2-relation GAT, N=100000, IN=OUT=128, E=320000/rel.
// Dtypes (R1-R4 verified): inputs f32, output f32.
// R11: 232.2us, gemm still top (64us): MFMA 3.8% (=2.4us real work), 85%
// stall. Spread bins bought 12us (line contention real); remaining stall =
// front-loaded atomic storm -- every wave blocks on its 2 returning atomics
// BEFORE starting GEMM (rank store consumes the return; vmcnt FIFO).
// R12: move the edge-atomic phase to the END of gemm -- per-wave the wait
// lands after all its compute retired; device-wide the 640K atomics spread
// across the kernel (staggered block finish, ~6 blocks/CU serial) instead of
// a prologue storm. dst loads also deferred. 7 dispatches.

typedef __bf16 bf16x8 __attribute__((ext_vector_type(8)));
typedef float f32x4 __attribute__((ext_vector_type(4)));

#define DIM 128
#define SPREAD 16   // deg bin spacing (x4B = 64B sector per bin)

// ---- prep: W^T (both rels) -> bf16 in exact B-fragment order ----
// entry e = ((rel*8 + ct)*4 + ko4)*64 + lane holds 8 bf16:
//   B[k = ko4*32 + (lane>>4)*8 + j][n = ct*16 + (lane&15)], j=0..7
__global__ __launch_bounds__(256) void prep_w_kernel(
    const float* __restrict__ W0, const float* __restrict__ W1,
    __bf16* __restrict__ wtf)
{
    const int e = blockIdx.x * 256 + threadIdx.x;   // 4096 entries
    if (e >= 4096) return;
    const int lane = e & 63;
    const int ko4  = (e >> 6) & 3;
    const int ct   = (e >> 8) & 7;
    const int rel  = e >> 11;
    const float* W = rel ? W1 : W0;
    const int n  = ct * 16 + (lane & 15);
    const int k0 = ko4 * 32 + (lane >> 4) * 8;
    bf16x8 v;
#pragma unroll
    for (int j = 0; j < 8; ++j) v[j] = (__bf16)W[(k0 + j) * DIM + n];
    *(bf16x8*)(wtf + (size_t)e * 8) = v;
}

// ---- wh_r = bf16(x) @ W_r + b_r (both rels), fused scores + deg/rank ----
// Block 256 = 4 waves; wave owns 16 rows; block 64 rows. No LDS for W:
// bfrags are wave-uniform coalesced 1KB global loads from wtf (L1-hit).
// Edge atomics (deg count + rank capture) run at kernel END so the L3-RMW
// round-trip overlaps other blocks' compute instead of front-loading.
__global__ __launch_bounds__(256) void gemm_wh_kernel(
    const float* __restrict__ x, const __bf16* __restrict__ wtf,
    const float* __restrict__ b0, const float* __restrict__ b1,
    const float* __restrict__ a0, const float* __restrict__ a1,
    const int* __restrict__ dst0, const int* __restrict__ dst1,
    unsigned* __restrict__ deg, unsigned* __restrict__ rank,
    __bf16* __restrict__ wh, float* __restrict__ s_src,
    float* __restrict__ s_dst, int N, int E)
{
    __shared__ __align__(16) __bf16 Cst[64 * 136];  // 17408 B C-staging
    const int tid = threadIdx.x;

    const int lane = tid & 63;
    const int wave = tid >> 6;
    const int quad = lane >> 4;
    const int mr   = lane & 15;

    const long row0 = (long)blockIdx.x * 64 + wave * 16;
    long arow = row0 + mr;
    if (arow >= N) arow = N - 1;               // clamp; results discarded
    const f32x4* xr = (const f32x4*)(x + arow * DIM);

    // full A slice for this lane: k = ko4*32 + quad*8 .. +7
    bf16x8 afrag[4];
#pragma unroll
    for (int ko4 = 0; ko4 < 4; ++ko4) {
        f32x4 lo = xr[ko4 * 8 + quad * 2], hi = xr[ko4 * 8 + quad * 2 + 1];
        afrag[ko4] = (bf16x8){ (__bf16)lo.x, (__bf16)lo.y, (__bf16)lo.z, (__bf16)lo.w,
                               (__bf16)hi.x, (__bf16)hi.y, (__bf16)hi.z, (__bf16)hi.w };
    }

    const bf16x8* wt = (const bf16x8*)wtf;

#pragma unroll
    for (int rel = 0; rel < 2; ++rel) {
        f32x4 zero = {0.f, 0.f, 0.f, 0.f};
        f32x4 acc[8];
#pragma unroll
        for (int t = 0; t < 8; ++t) acc[t] = zero;

#pragma unroll
        for (int ko4 = 0; ko4 < 4; ++ko4) {
#pragma unroll
            for (int ct = 0; ct < 8; ++ct) {
                bf16x8 bfrag = wt[((rel * 8 + ct) * 4 + ko4) * 64 + lane];
                acc[ct] = __builtin_amdgcn_mfma_f32_16x16x32_bf16(afrag[ko4], bfrag, acc[ct], 0, 0, 0);
            }
        }

        const float* bias = rel ? b1 : b0;
        const float* a    = rel ? a1 : a0;
        // C/D layout: col = ct*16+mr, row = quad*4+rr [m89-verified]
        float psr[4] = {0.f, 0.f, 0.f, 0.f};
        float pdr[4] = {0.f, 0.f, 0.f, 0.f};
#pragma unroll
        for (int ct = 0; ct < 8; ++ct) {
            const int c = ct * 16 + mr;
            const float bn = bias[c];
            const float asc = a[c], adc = a[DIM + c];
#pragma unroll
            for (int rr = 0; rr < 4; ++rr) {
                const float wv = acc[ct][rr] + bn;
                Cst[(wave * 16 + quad * 4 + rr) * 136 + c] = (__bf16)wv;
                psr[rr] += asc * wv;
                pdr[rr] += adc * wv;
            }
        }
#pragma unroll
        for (int off = 1; off < 16; off <<= 1) {
#pragma unroll
            for (int rr = 0; rr < 4; ++rr) {
                psr[rr] += __shfl_xor(psr[rr], off);
                pdr[rr] += __shfl_xor(pdr[rr], off);
            }
        }
        if (mr == 0) {
#pragma unroll
            for (int rr = 0; rr < 4; ++rr) {
                const long orow = row0 + quad * 4 + rr;
                if (orow < N) {
                    s_src[(size_t)rel * N + orow] = psr[rr];
                    s_dst[(size_t)rel * N + orow] = pdr[rr];
                }
            }
        }
        __syncthreads();                        // staging complete
        // coalesced read-back: 1024 chunks of 16B
#pragma unroll
        for (int i = 0; i < 4; ++i) {
            const int chunk = tid + 256 * i;
            const int row = chunk >> 4, c8 = chunk & 15;
            bf16x8 v = *(const bf16x8*)&Cst[row * 136 + c8 * 8];
            const long grow = (long)blockIdx.x * 64 + row;
            if (grow < N)
                *(bf16x8*)(wh + ((size_t)rel * N + grow) * DIM + c8 * 8) = v;
        }
        __syncthreads();                        // before rel1 re-stages Cst
    }

    // deferred edge-atomic phase: deg count + rank capture (spread bins).
    // All GEMM vmem has retired; the atomic round-trip stalls only this
    // wave's tail while other resident blocks keep computing.
    {
        const int gid = blockIdx.x * 256 + tid;
        if (gid < E) {
            const int d0 = dst0[gid], d1 = dst1[gid];
            const unsigned r0 = atomicAdd(deg + (size_t)d0 * SPREAD, 1u);
            const unsigned r1 = atomicAdd(deg + ((size_t)N + d1) * SPREAD, 1u);
            rank[gid]     = r0;
            rank[E + gid] = r1;
        }
    }
}

// ---------------- CSR scan pass 1: per-block inclusive scan ----------------
__global__ __launch_bounds__(256) void scanA_kernel(
    const unsigned* __restrict__ deg, unsigned* __restrict__ tmp,
    unsigned* __restrict__ bsum, int n)
{
    __shared__ unsigned s[256];
    const int t = threadIdx.x;
    const int i = blockIdx.x * 256 + t;
    unsigned v = (i < n) ? deg[(size_t)i * SPREAD] : 0u;
    s[t] = v;
    __syncthreads();
#pragma unroll
    for (int off = 1; off < 256; off <<= 1) {
        unsigned add = (t >= off) ? s[t - off] : 0u;
        __syncthreads();
        s[t] += add;
        __syncthreads();
    }
    if (i < n) tmp[i] = s[t] - v;            // exclusive within block
    if (t == 255) bsum[blockIdx.x] = s[t];   // block total
}

// ---- CSR scan pass 2: each block re-scans bsum locally, writes rowptr ----
// nb <= 1024 (782 here)
__global__ __launch_bounds__(256) void scan2_kernel(
    const unsigned* __restrict__ tmp, const unsigned* __restrict__ bsum,
    const unsigned* __restrict__ deg, unsigned* __restrict__ rowptr,
    int n, int nb)
{
    __shared__ unsigned s[256];
    __shared__ unsigned ex[1024];
    const int t = threadIdx.x;
    unsigned loc[4], sum = 0u;
#pragma unroll
    for (int k = 0; k < 4; ++k) {
        int idx = t * 4 + k;
        loc[k] = (idx < nb) ? bsum[idx] : 0u;
        sum += loc[k];
    }
    s[t] = sum;
    __syncthreads();
#pragma unroll
    for (int off = 1; off < 256; off <<= 1) {
        unsigned add = (t >= off) ? s[t - off] : 0u;
        __syncthreads();
        s[t] += add;
        __syncthreads();
    }
    unsigned run = s[t] - sum;
#pragma unroll
    for (int k = 0; k < 4; ++k) {
        ex[t * 4 + k] = run;
        run += loc[k];
    }
    __syncthreads();
    const unsigned pref = ex[blockIdx.x];
    const int i = blockIdx.x * 256 + t;
    if (i < n) {
        unsigned val = tmp[i] + pref;
        rowptr[i] = val;
        if (i == n - 1) rowptr[n] = val + deg[(size_t)i * SPREAD];
    }
}

// ---- CSR build + edge scores: fully atomic-free streaming ----
// slot = rowptr[dst] + rank (rank captured in gemm's deg atomic). Chain is
// independent loads -> expf -> fire-and-forget store. Denominators now
// computed inline by aggregate.
__global__ __launch_bounds__(256) void fill_kernel(
    const int* __restrict__ src0, const int* __restrict__ dst0,
    const int* __restrict__ src1, const int* __restrict__ dst1,
    const float* __restrict__ s_src, const float* __restrict__ s_dst,
    const unsigned* __restrict__ rowptr, const unsigned* __restrict__ rank,
    uint2* __restrict__ sorted, int N, int E)
{
    const int i = blockIdx.x * 256 + threadIdx.x;
    if (i >= E) return;
    const int s0 = src0[i], d0 = dst0[i];
    const int s1 = src1[i], d1 = dst1[i];
    const unsigned p0 = rowptr[d0] + rank[i];
    const unsigned p1 = rowptr[N + d1] + rank[E + i];

    float v0 = s_src[s0] + s_dst[d0];
    v0 = v0 > 0.f ? v0 : 0.01f * v0;            // leaky_relu slope 0.01
    const float e0 = __expf(v0);
    float v1 = s_src[N + s1] + s_dst[N + d1];
    v1 = v1 > 0.f ? v1 : 0.01f * v1;
    const float e1 = __expf(v1);

    sorted[p0] = make_uint2((unsigned)s0, __float_as_uint(e0));
    sorted[p1] = make_uint2((unsigned)s1, __float_as_uint(e1));
}

// ---------------- gather-sum with inline softmax denominators ----------------
// One wave per dst. Both rels merged into one virtual edge list (len T);
// 4 subgroups x 2 slots = 8 edges in flight per round. Branchless: invalid
// slots clamp idx to 0 (L1-hit dummy row) with weight 0. Per-rel unnormalized
// accumulators a0/a1 + denominators l0/l1 built inline (rel select via zeroed
// weights); single cross-subgroup combine of 18 values, normalize, write.
__global__ __launch_bounds__(256) void aggregate_kernel(
    const unsigned* __restrict__ rowptr, const uint2* __restrict__ sorted,
    const __bf16* __restrict__ wh, float* __restrict__ out, int N)
{
    const int tid  = threadIdx.x;
    const int lane = tid & 63;
    const int sub  = lane >> 4;
    const int mr   = lane & 15;
    int d = blockIdx.x * 4 + (tid >> 6);
    if (d >= N) return;
    d = __builtin_amdgcn_readfirstlane(d);      // wave-uniform -> s_loads

    const unsigned beg0 = rowptr[d],     end0 = rowptr[d + 1];
    const unsigned beg1 = rowptr[N + d], end1 = rowptr[N + d + 1];
    const unsigned len0 = end0 - beg0;
    const unsigned T    = len0 + (end1 - beg1);

    float acc0[8], acc1[8], l0 = 0.f, l1 = 0.f;
#pragma unroll
    for (int k = 0; k < 8; ++k) { acc0[k] = 0.f; acc1[k] = 0.f; }

    const size_t whstride = (size_t)N * DIM;

    for (unsigned t0 = 0; t0 < T; t0 += 8) {
        const unsigned tA = t0 + sub, tB = tA + 4;
        const bool vA = tA < T, vB = tB < T;
        const bool rA = tA >= len0, rB = tB >= len0;

        unsigned iA = rA ? beg1 + (tA - len0) : beg0 + tA;
        unsigned iB = rB ? beg1 + (tB - len0) : beg0 + tB;
        iA = vA ? iA : 0u;
        iB = vB ? iB : 0u;

        const uint2 eA = sorted[iA];
        const uint2 eB = sorted[iB];

        const float evA = vA ? __uint_as_float(eA.y) : 0.f;
        const float evB = vB ? __uint_as_float(eB.y) : 0.f;
        const float wA0 = rA ? 0.f : evA, wA1 = rA ? evA : 0.f;
        const float wB0 = rB ? 0.f : evB, wB1 = rB ? evB : 0.f;
        l0 += wA0 + wB0;
        l1 += wA1 + wB1;

        const bf16x8 wA = *(const bf16x8*)(wh + (rA ? whstride : 0)
                                              + (size_t)eA.x * DIM + mr * 8);
        const bf16x8 wB = *(const bf16x8*)(wh + (rB ? whstride : 0)
                                              + (size_t)eB.x * DIM + mr * 8);
#pragma unroll
        for (int k = 0; k < 8; ++k) {
            const float fA = (float)wA[k], fB = (float)wB[k];
            acc0[k] += wA0 * fA + wB0 * fB;
            acc1[k] += wA1 * fA + wB1 * fB;
        }
    }

    // single combine across 4 subgroups (16+2 values)
#pragma unroll
    for (int k = 0; k < 8; ++k) {
        acc0[k] += __shfl_xor(acc0[k], 16);
        acc0[k] += __shfl_xor(acc0[k], 32);
        acc1[k] += __shfl_xor(acc1[k], 16);
        acc1[k] += __shfl_xor(acc1[k], 32);
    }
    l0 += __shfl_xor(l0, 16); l0 += __shfl_xor(l0, 32);
    l1 += __shfl_xor(l1, 16); l1 += __shfl_xor(l1, 32);

    const float inv0 = l0 > 0.f ? 1.f / l0 : 0.f;
    const float inv1 = l1 > 0.f ? 1.f / l1 : 0.f;

    if (sub == 0) {                             // 16 lanes cover the 512B row
        float o[8];
#pragma unroll
        for (int k = 0; k < 8; ++k) o[k] = acc0[k] * inv0 + acc1[k] * inv1;
        float4 v0 = {o[0], o[1], o[2], o[3]};
        float4 v1 = {o[4], o[5], o[6], o[7]};
        float* op = out + (size_t)d * DIM + mr * 8;
        *(float4*)op       = v0;
        *(float4*)(op + 4) = v1;
    }
}

extern "C" void kernel_launch(void* const* d_in, const int* in_sizes, int n_in,
                              void* d_out, int out_size, void* d_ws, size_t ws_size,
                              hipStream_t stream) {
    const float* x = (const float*)d_in[0];
    const int* srcs[2] = {(const int*)d_in[1], (const int*)d_in[3]};
    const int* dsts[2] = {(const int*)d_in[2], (const int*)d_in[4]};
    const float* Ws[2] = {(const float*)d_in[5], (const float*)d_in[8]};
    const float* Bs[2] = {(const float*)d_in[6], (const float*)d_in[9]};
    const float* As[2] = {(const float*)d_in[7], (const float*)d_in[10]};

    const int N = in_sizes[0] / DIM;
    const int E = in_sizes[1];
    const int n2 = 2 * N;
    const int nb = (n2 + 255) / 256;            // scan blocks (782)
    float* out = (float*)d_out;

    // workspace carve-up (~75 MB); all chunks 8B-aligned
    char* p = (char*)d_ws;
    __bf16*   wh     = (__bf16*)p;   p += (size_t)n2 * DIM * 2;       // wh0|wh1
    __bf16*   wtf    = (__bf16*)p;   p += (size_t)4096 * 8 * 2;       // 64KB frag-W
    float*    s_src  = (float*)p;    p += (size_t)n2 * 4;
    float*    s_dst  = (float*)p;    p += (size_t)n2 * 4;
    unsigned* deg    = (unsigned*)p; p += (size_t)n2 * SPREAD * 4;    // 12.8MB spread
    unsigned* tmp    = (unsigned*)p; p += (size_t)n2 * 4;
    unsigned* rowptr = (unsigned*)p; p += (size_t)(n2 + 2) * 4;       // pad to 8B
    unsigned* rank   = (unsigned*)p; p += (size_t)2 * E * 4;          // per-edge rank
    uint2*    sorted = (uint2*)p;    p += (size_t)2 * E * 8;          // {src, e}
    unsigned* bsum   = (unsigned*)p; p += (size_t)nb * 4;

    hipMemsetAsync(deg, 0, (size_t)n2 * SPREAD * 4, stream);
    prep_w_kernel<<<16, 256, 0, stream>>>(Ws[0], Ws[1], wtf);

    // gemm grid covers both row tiles (1563) and edge count (1250)
    gemm_wh_kernel<<<(N + 63) / 64, 256, 0, stream>>>(
        x, wtf, Bs[0], Bs[1], As[0], As[1],
        dsts[0], dsts[1], deg, rank, wh, s_src, s_dst, N, E);

    scanA_kernel<<<nb, 256, 0, stream>>>(deg, tmp, bsum, n2);
    scan2_kernel<<<nb, 256, 0, stream>>>(tmp, bsum, deg, rowptr, n2, nb);
    fill_kernel<<<(E + 255) / 256, 256, 0, stream>>>(
        srcs[0], dsts[0], srcs[1], dsts[1], s_src, s_dst,
        rowptr, rank, sorted, N, E);
    aggregate_kernel<<<(N + 3) / 4, 256, 0, stream>>>(
        rowptr, sorted, wh, out, N);
}

// Round 5
// 224.253 us; speedup vs baseline: 1.1924x; 1.0172x over previous
//
#include <hip/hip_runtime.h>
#include <hip/hip_bf16.h>

// HeteroGAT: 2-relation GAT, N=100000, IN=OUT=128, E=320000/rel.
// Dtypes (R1-R4 verified): inputs f32, output f32.
// R12: 228.1us, gemm 60.5us: tail-deferred atomics only bought 4us -- blocks
// run in ~2 synchronized generations, so the 640K-atomic drain (R9 calib:
// ~19.5G/s => ~33us device floor) still bursts while compute waves retire.
// R13: 128 dedicated atomic-feeder blocks (dispatched FIRST, resident all
// kernel) grid-stride the 2E edge atomics with natural completion
// backpressure -> fabric RMW units fed continuously from t=0; the 1563 GEMM
// blocks are now 100% atomic-free. Kernel ~ max(atomic floor, pure GEMM)
// instead of their sum. 7 dispatches.

typedef __bf16 bf16x8 __attribute__((ext_vector_type(8)));
typedef float f32x4 __attribute__((ext_vector_type(4)));

#define DIM 128
#define SPREAD 16        // deg bin spacing (x4B = 64B sector per bin)
#define ATOMIC_BLOCKS 128

// ---- prep: W^T (both rels) -> bf16 in exact B-fragment order ----
// entry e = ((rel*8 + ct)*4 + ko4)*64 + lane holds 8 bf16:
//   B[k = ko4*32 + (lane>>4)*8 + j][n = ct*16 + (lane&15)], j=0..7
__global__ __launch_bounds__(256) void prep_w_kernel(
    const float* __restrict__ W0, const float* __restrict__ W1,
    __bf16* __restrict__ wtf)
{
    const int e = blockIdx.x * 256 + threadIdx.x;   // 4096 entries
    if (e >= 4096) return;
    const int lane = e & 63;
    const int ko4  = (e >> 6) & 3;
    const int ct   = (e >> 8) & 7;
    const int rel  = e >> 11;
    const float* W = rel ? W1 : W0;
    const int n  = ct * 16 + (lane & 15);
    const int k0 = ko4 * 32 + (lane >> 4) * 8;
    bf16x8 v;
#pragma unroll
    for (int j = 0; j < 8; ++j) v[j] = (__bf16)W[(k0 + j) * DIM + n];
    *(bf16x8*)(wtf + (size_t)e * 8) = v;
}

// ---- wh_r = bf16(x) @ W_r + b_r (both rels) + feeder atomic blocks ----
// blockIdx < ATOMIC_BLOCKS: atomic-feeder role. Grid-stride the flat 2E edge
// list, 2 edges in flight per thread; each wave's issue rate is backpressured
// by atomic completion (FIFO vmcnt), spreading the 640K RMWs evenly across
// the whole kernel. Remaining blocks: pure GEMM, no LDS for W (bfrags are
// wave-uniform coalesced 1KB loads from wtf, L1-hit).
__global__ __launch_bounds__(256) void gemm_wh_kernel(
    const float* __restrict__ x, const __bf16* __restrict__ wtf,
    const float* __restrict__ b0, const float* __restrict__ b1,
    const float* __restrict__ a0, const float* __restrict__ a1,
    const int* __restrict__ dst0, const int* __restrict__ dst1,
    unsigned* __restrict__ deg, unsigned* __restrict__ rank,
    __bf16* __restrict__ wh, float* __restrict__ s_src,
    float* __restrict__ s_dst, int N, int E)
{
    __shared__ __align__(16) __bf16 Cst[64 * 136];  // 17408 B C-staging
    const int tid = threadIdx.x;

    if (blockIdx.x < ATOMIC_BLOCKS) {
        // flat idx: [0,E) = rel0 edge, [E,2E) = rel1 edge (matches rank[]
        // layout consumed by fill: rank[i] / rank[E+i]).
        const int TF  = ATOMIC_BLOCKS * 256;
        const int TOT = 2 * E;
        for (int ia = blockIdx.x * 256 + tid; ia < TOT; ia += 2 * TF) {
            const int ib = ia + TF;
            const bool vb = ib < TOT;
            const unsigned ba = (unsigned)(ia < E ? dst0[ia] : N + dst1[ia - E]);
            const unsigned ra = atomicAdd(deg + (size_t)ba * SPREAD, 1u);
            unsigned rb = 0u;
            if (vb) {
                const unsigned bb = (unsigned)(ib < E ? dst0[ib] : N + dst1[ib - E]);
                rb = atomicAdd(deg + (size_t)bb * SPREAD, 1u);
            }
            rank[ia] = ra;
            if (vb) rank[ib] = rb;
        }
        return;
    }
    const int bx = blockIdx.x - ATOMIC_BLOCKS;

    const int lane = tid & 63;
    const int wave = tid >> 6;
    const int quad = lane >> 4;
    const int mr   = lane & 15;

    const long row0 = (long)bx * 64 + wave * 16;
    long arow = row0 + mr;
    if (arow >= N) arow = N - 1;               // clamp; results discarded
    const f32x4* xr = (const f32x4*)(x + arow * DIM);

    // full A slice for this lane: k = ko4*32 + quad*8 .. +7
    bf16x8 afrag[4];
#pragma unroll
    for (int ko4 = 0; ko4 < 4; ++ko4) {
        f32x4 lo = xr[ko4 * 8 + quad * 2], hi = xr[ko4 * 8 + quad * 2 + 1];
        afrag[ko4] = (bf16x8){ (__bf16)lo.x, (__bf16)lo.y, (__bf16)lo.z, (__bf16)lo.w,
                               (__bf16)hi.x, (__bf16)hi.y, (__bf16)hi.z, (__bf16)hi.w };
    }

    const bf16x8* wt = (const bf16x8*)wtf;

#pragma unroll
    for (int rel = 0; rel < 2; ++rel) {
        f32x4 zero = {0.f, 0.f, 0.f, 0.f};
        f32x4 acc[8];
#pragma unroll
        for (int t = 0; t < 8; ++t) acc[t] = zero;

#pragma unroll
        for (int ko4 = 0; ko4 < 4; ++ko4) {
#pragma unroll
            for (int ct = 0; ct < 8; ++ct) {
                bf16x8 bfrag = wt[((rel * 8 + ct) * 4 + ko4) * 64 + lane];
                acc[ct] = __builtin_amdgcn_mfma_f32_16x16x32_bf16(afrag[ko4], bfrag, acc[ct], 0, 0, 0);
            }
        }

        const float* bias = rel ? b1 : b0;
        const float* a    = rel ? a1 : a0;
        // C/D layout: col = ct*16+mr, row = quad*4+rr [m89-verified]
        float psr[4] = {0.f, 0.f, 0.f, 0.f};
        float pdr[4] = {0.f, 0.f, 0.f, 0.f};
#pragma unroll
        for (int ct = 0; ct < 8; ++ct) {
            const int c = ct * 16 + mr;
            const float bn = bias[c];
            const float asc = a[c], adc = a[DIM + c];
#pragma unroll
            for (int rr = 0; rr < 4; ++rr) {
                const float wv = acc[ct][rr] + bn;
                Cst[(wave * 16 + quad * 4 + rr) * 136 + c] = (__bf16)wv;
                psr[rr] += asc * wv;
                pdr[rr] += adc * wv;
            }
        }
#pragma unroll
        for (int off = 1; off < 16; off <<= 1) {
#pragma unroll
            for (int rr = 0; rr < 4; ++rr) {
                psr[rr] += __shfl_xor(psr[rr], off);
                pdr[rr] += __shfl_xor(pdr[rr], off);
            }
        }
        if (mr == 0) {
#pragma unroll
            for (int rr = 0; rr < 4; ++rr) {
                const long orow = row0 + quad * 4 + rr;
                if (orow < N) {
                    s_src[(size_t)rel * N + orow] = psr[rr];
                    s_dst[(size_t)rel * N + orow] = pdr[rr];
                }
            }
        }
        __syncthreads();                        // staging complete
        // coalesced read-back: 1024 chunks of 16B
#pragma unroll
        for (int i = 0; i < 4; ++i) {
            const int chunk = tid + 256 * i;
            const int row = chunk >> 4, c8 = chunk & 15;
            bf16x8 v = *(const bf16x8*)&Cst[row * 136 + c8 * 8];
            const long grow = (long)bx * 64 + row;
            if (grow < N)
                *(bf16x8*)(wh + ((size_t)rel * N + grow) * DIM + c8 * 8) = v;
        }
        __syncthreads();                        // before rel1 re-stages Cst
    }
}

// ---------------- CSR scan pass 1: per-block inclusive scan ----------------
__global__ __launch_bounds__(256) void scanA_kernel(
    const unsigned* __restrict__ deg, unsigned* __restrict__ tmp,
    unsigned* __restrict__ bsum, int n)
{
    __shared__ unsigned s[256];
    const int t = threadIdx.x;
    const int i = blockIdx.x * 256 + t;
    unsigned v = (i < n) ? deg[(size_t)i * SPREAD] : 0u;
    s[t] = v;
    __syncthreads();
#pragma unroll
    for (int off = 1; off < 256; off <<= 1) {
        unsigned add = (t >= off) ? s[t - off] : 0u;
        __syncthreads();
        s[t] += add;
        __syncthreads();
    }
    if (i < n) tmp[i] = s[t] - v;            // exclusive within block
    if (t == 255) bsum[blockIdx.x] = s[t];   // block total
}

// ---- CSR scan pass 2: each block re-scans bsum locally, writes rowptr ----
// nb <= 1024 (782 here)
__global__ __launch_bounds__(256) void scan2_kernel(
    const unsigned* __restrict__ tmp, const unsigned* __restrict__ bsum,
    const unsigned* __restrict__ deg, unsigned* __restrict__ rowptr,
    int n, int nb)
{
    __shared__ unsigned s[256];
    __shared__ unsigned ex[1024];
    const int t = threadIdx.x;
    unsigned loc[4], sum = 0u;
#pragma unroll
    for (int k = 0; k < 4; ++k) {
        int idx = t * 4 + k;
        loc[k] = (idx < nb) ? bsum[idx] : 0u;
        sum += loc[k];
    }
    s[t] = sum;
    __syncthreads();
#pragma unroll
    for (int off = 1; off < 256; off <<= 1) {
        unsigned add = (t >= off) ? s[t - off] : 0u;
        __syncthreads();
        s[t] += add;
        __syncthreads();
    }
    unsigned run = s[t] - sum;
#pragma unroll
    for (int k = 0; k < 4; ++k) {
        ex[t * 4 + k] = run;
        run += loc[k];
    }
    __syncthreads();
    const unsigned pref = ex[blockIdx.x];
    const int i = blockIdx.x * 256 + t;
    if (i < n) {
        unsigned val = tmp[i] + pref;
        rowptr[i] = val;
        if (i == n - 1) rowptr[n] = val + deg[(size_t)i * SPREAD];
    }
}

// ---- CSR build + edge scores: fully atomic-free streaming ----
// slot = rowptr[dst] + rank (rank captured by feeder blocks). Chain is
// independent loads -> expf -> fire-and-forget store. Denominators computed
// inline by aggregate.
__global__ __launch_bounds__(256) void fill_kernel(
    const int* __restrict__ src0, const int* __restrict__ dst0,
    const int* __restrict__ src1, const int* __restrict__ dst1,
    const float* __restrict__ s_src, const float* __restrict__ s_dst,
    const unsigned* __restrict__ rowptr, const unsigned* __restrict__ rank,
    uint2* __restrict__ sorted, int N, int E)
{
    const int i = blockIdx.x * 256 + threadIdx.x;
    if (i >= E) return;
    const int s0 = src0[i], d0 = dst0[i];
    const int s1 = src1[i], d1 = dst1[i];
    const unsigned p0 = rowptr[d0] + rank[i];
    const unsigned p1 = rowptr[N + d1] + rank[E + i];

    float v0 = s_src[s0] + s_dst[d0];
    v0 = v0 > 0.f ? v0 : 0.01f * v0;            // leaky_relu slope 0.01
    const float e0 = __expf(v0);
    float v1 = s_src[N + s1] + s_dst[N + d1];
    v1 = v1 > 0.f ? v1 : 0.01f * v1;
    const float e1 = __expf(v1);

    sorted[p0] = make_uint2((unsigned)s0, __float_as_uint(e0));
    sorted[p1] = make_uint2((unsigned)s1, __float_as_uint(e1));
}

// ---------------- gather-sum with inline softmax denominators ----------------
// One wave per dst. Both rels merged into one virtual edge list (len T);
// 4 subgroups x 2 slots = 8 edges in flight per round. Branchless: invalid
// slots clamp idx to 0 (L1-hit dummy row) with weight 0. Per-rel unnormalized
// accumulators a0/a1 + denominators l0/l1 built inline (rel select via zeroed
// weights); single cross-subgroup combine of 18 values, normalize, write.
__global__ __launch_bounds__(256) void aggregate_kernel(
    const unsigned* __restrict__ rowptr, const uint2* __restrict__ sorted,
    const __bf16* __restrict__ wh, float* __restrict__ out, int N)
{
    const int tid  = threadIdx.x;
    const int lane = tid & 63;
    const int sub  = lane >> 4;
    const int mr   = lane & 15;
    int d = blockIdx.x * 4 + (tid >> 6);
    if (d >= N) return;
    d = __builtin_amdgcn_readfirstlane(d);      // wave-uniform -> s_loads

    const unsigned beg0 = rowptr[d],     end0 = rowptr[d + 1];
    const unsigned beg1 = rowptr[N + d], end1 = rowptr[N + d + 1];
    const unsigned len0 = end0 - beg0;
    const unsigned T    = len0 + (end1 - beg1);

    float acc0[8], acc1[8], l0 = 0.f, l1 = 0.f;
#pragma unroll
    for (int k = 0; k < 8; ++k) { acc0[k] = 0.f; acc1[k] = 0.f; }

    const size_t whstride = (size_t)N * DIM;

    for (unsigned t0 = 0; t0 < T; t0 += 8) {
        const unsigned tA = t0 + sub, tB = tA + 4;
        const bool vA = tA < T, vB = tB < T;
        const bool rA = tA >= len0, rB = tB >= len0;

        unsigned iA = rA ? beg1 + (tA - len0) : beg0 + tA;
        unsigned iB = rB ? beg1 + (tB - len0) : beg0 + tB;
        iA = vA ? iA : 0u;
        iB = vB ? iB : 0u;

        const uint2 eA = sorted[iA];
        const uint2 eB = sorted[iB];

        const float evA = vA ? __uint_as_float(eA.y) : 0.f;
        const float evB = vB ? __uint_as_float(eB.y) : 0.f;
        const float wA0 = rA ? 0.f : evA, wA1 = rA ? evA : 0.f;
        const float wB0 = rB ? 0.f : evB, wB1 = rB ? evB : 0.f;
        l0 += wA0 + wB0;
        l1 += wA1 + wB1;

        const bf16x8 wA = *(const bf16x8*)(wh + (rA ? whstride : 0)
                                              + (size_t)eA.x * DIM + mr * 8);
        const bf16x8 wB = *(const bf16x8*)(wh + (rB ? whstride : 0)
                                              + (size_t)eB.x * DIM + mr * 8);
#pragma unroll
        for (int k = 0; k < 8; ++k) {
            const float fA = (float)wA[k], fB = (float)wB[k];
            acc0[k] += wA0 * fA + wB0 * fB;
            acc1[k] += wA1 * fA + wB1 * fB;
        }
    }

    // single combine across 4 subgroups (16+2 values)
#pragma unroll
    for (int k = 0; k < 8; ++k) {
        acc0[k] += __shfl_xor(acc0[k], 16);
        acc0[k] += __shfl_xor(acc0[k], 32);
        acc1[k] += __shfl_xor(acc1[k], 16);
        acc1[k] += __shfl_xor(acc1[k], 32);
    }
    l0 += __shfl_xor(l0, 16); l0 += __shfl_xor(l0, 32);
    l1 += __shfl_xor(l1, 16); l1 += __shfl_xor(l1, 32);

    const float inv0 = l0 > 0.f ? 1.f / l0 : 0.f;
    const float inv1 = l1 > 0.f ? 1.f / l1 : 0.f;

    if (sub == 0) {                             // 16 lanes cover the 512B row
        float o[8];
#pragma unroll
        for (int k = 0; k < 8; ++k) o[k] = acc0[k] * inv0 + acc1[k] * inv1;
        float4 v0 = {o[0], o[1], o[2], o[3]};
        float4 v1 = {o[4], o[5], o[6], o[7]};
        float* op = out + (size_t)d * DIM + mr * 8;
        *(float4*)op       = v0;
        *(float4*)(op + 4) = v1;
    }
}

extern "C" void kernel_launch(void* const* d_in, const int* in_sizes, int n_in,
                              void* d_out, int out_size, void* d_ws, size_t ws_size,
                              hipStream_t stream) {
    const float* x = (const float*)d_in[0];
    const int* srcs[2] = {(const int*)d_in[1], (const int*)d_in[3]};
    const int* dsts[2] = {(const int*)d_in[2], (const int*)d_in[4]};
    const float* Ws[2] = {(const float*)d_in[5], (const float*)d_in[8]};
    const float* Bs[2] = {(const float*)d_in[6], (const float*)d_in[9]};
    const float* As[2] = {(const float*)d_in[7], (const float*)d_in[10]};

    const int N = in_sizes[0] / DIM;
    const int E = in_sizes[1];
    const int n2 = 2 * N;
    const int nb = (n2 + 255) / 256;            // scan blocks (782)
    float* out = (float*)d_out;

    // workspace carve-up (~75 MB); all chunks 8B-aligned
    char* p = (char*)d_ws;
    __bf16*   wh     = (__bf16*)p;   p += (size_t)n2 * DIM * 2;       // wh0|wh1
    __bf16*   wtf    = (__bf16*)p;   p += (size_t)4096 * 8 * 2;       // 64KB frag-W
    float*    s_src  = (float*)p;    p += (size_t)n2 * 4;
    float*    s_dst  = (float*)p;    p += (size_t)n2 * 4;
    unsigned* deg    = (unsigned*)p; p += (size_t)n2 * SPREAD * 4;    // 12.8MB spread
    unsigned* tmp    = (unsigned*)p; p += (size_t)n2 * 4;
    unsigned* rowptr = (unsigned*)p; p += (size_t)(n2 + 2) * 4;       // pad to 8B
    unsigned* rank   = (unsigned*)p; p += (size_t)2 * E * 4;          // per-edge rank
    uint2*    sorted = (uint2*)p;    p += (size_t)2 * E * 8;          // {src, e}
    unsigned* bsum   = (unsigned*)p; p += (size_t)nb * 4;

    hipMemsetAsync(deg, 0, (size_t)n2 * SPREAD * 4, stream);
    prep_w_kernel<<<16, 256, 0, stream>>>(Ws[0], Ws[1], wtf);

    // grid = 128 atomic-feeder blocks (dispatched first) + 1563 GEMM tiles
    gemm_wh_kernel<<<ATOMIC_BLOCKS + (N + 63) / 64, 256, 0, stream>>>(
        x, wtf, Bs[0], Bs[1], As[0], As[1],
        dsts[0], dsts[1], deg, rank, wh, s_src, s_dst, N, E);

    scanA_kernel<<<nb, 256, 0, stream>>>(deg, tmp, bsum, n2);
    scan2_kernel<<<nb, 256, 0, stream>>>(tmp, bsum, deg, rowptr, n2, nb);
    fill_kernel<<<(E + 255) / 256, 256, 0, stream>>>(
        srcs[0], dsts[0], srcs[1], dsts[1], s_src, s_dst,
        rowptr, rank, sorted, N, E);
    aggregate_kernel<<<(N + 3) / 4, 256, 0, stream>>>(
        rowptr, sorted, wh, out, N);
}